// Round 1
// baseline (97.955 us; speedup 1.0000x reference)
//
#include <hip/hip_runtime.h>

// CollisionLoss: pos [65536, 24, 3] fp32 -> scalar.
// Static mask: point 0 excluded, pair (2,3) excluded, diagonal excluded.
// Symmetric mask => evaluate only i<j pairs; numerator and denominator both
// halve, ratio unchanged. dist<0.5 <=> sq<0.25; exp(-(dist/0.5)^2)=exp(-4*sq)
// => no sqrt needed.

#define NPTS 24
#define BLK 64          // one wave per block; one thread per batch element
#define LDS_STRIDE 73   // 73 mod 32 = 9 (odd) -> 2 lanes/bank on reads (free)

__global__ __launch_bounds__(BLK)
void collision_main(const float* __restrict__ pos, float* __restrict__ ws) {
    __shared__ float lds[BLK * LDS_STRIDE];
    const int t = threadIdx.x;                 // 0..63
    const int blockBase = blockIdx.x * BLK;    // first batch handled by block

    // --- Stage 64 batches * 72 floats = 1152 float4, coalesced ---
    const float4* gp = (const float4*)pos + (size_t)blockBase * 18; // 18 f4/batch
    #pragma unroll
    for (int k = 0; k < 18; ++k) {
        int f4 = t + k * BLK;        // 0..1151 ; 18 f4 per batch, no straddle
        float4 v = gp[f4];
        int b  = f4 / 18;
        int e4 = f4 % 18;
        float* dst = &lds[b * LDS_STRIDE + e4 * 4];
        dst[0] = v.x; dst[1] = v.y; dst[2] = v.z; dst[3] = v.w;
    }
    __syncthreads();

    // --- Pull own batch's 24 points into registers ---
    float px[NPTS], py[NPTS], pz[NPTS];
    const float* src = &lds[t * LDS_STRIDE];
    #pragma unroll
    for (int i = 0; i < NPTS; ++i) {
        px[i] = src[3 * i + 0];
        py[i] = src[3 * i + 1];
        pz[i] = src[3 * i + 2];
    }

    // --- 252 unordered pairs (i<j, i>=1, skip (2,3)) ---
    float s = 0.0f, c = 0.0f;
    #pragma unroll
    for (int i = 1; i < NPTS; ++i) {
        #pragma unroll
        for (int j = i + 1; j < NPTS; ++j) {
            if (i == 2 && j == 3) continue;   // compile-time eliminated
            float dx = px[i] - px[j];
            float dy = py[i] - py[j];
            float dz = pz[i] - pz[j];
            float sq = fmaf(dx, dx, fmaf(dy, dy, dz * dz));
            bool  w  = sq < 0.25f;
            float e  = __expf(-4.0f * sq);
            s += w ? e : 0.0f;                // v_cndmask + v_add (no branch)
            c += w ? 1.0f : 0.0f;
        }
    }

    // --- Wave-64 reduction, then one atomic pair per block ---
    #pragma unroll
    for (int off = 32; off >= 1; off >>= 1) {
        s += __shfl_down(s, off, 64);
        c += __shfl_down(c, off, 64);
    }
    if (t == 0) {
        atomicAdd(&ws[0], s);   // device-scope by default on CDNA4
        atomicAdd(&ws[1], c);
    }
}

__global__ void collision_final(const float* __restrict__ ws,
                                float* __restrict__ out) {
    float s = ws[0], c = ws[1];
    float total = (c > 0.0f) ? (s / fmaxf(c, 1.0f)) : 0.0f;
    out[0] = total + 1e-6f;
}

extern "C" void kernel_launch(void* const* d_in, const int* in_sizes, int n_in,
                              void* d_out, int out_size, void* d_ws, size_t ws_size,
                              hipStream_t stream) {
    const float* pos = (const float*)d_in[0];
    float* out = (float*)d_out;
    float* ws  = (float*)d_ws;

    const int B = in_sizes[0] / (NPTS * 3);   // 65536
    const int nblocks = B / BLK;              // 1024

    // d_ws is re-poisoned to 0xAA before every launch -> zero the accumulators.
    hipMemsetAsync(ws, 0, 2 * sizeof(float), stream);
    collision_main<<<nblocks, BLK, 0, stream>>>(pos, ws);
    collision_final<<<1, 1, 0, stream>>>(ws, out);
}

// Round 2
// 68.961 us; speedup vs baseline: 1.4205x; 1.4205x over previous
//
#include <hip/hip_runtime.h>

// CollisionLoss: pos [65536, 24, 3] fp32 -> scalar.
// Static mask: point 0 excluded, pair (2,3) excluded, diagonal excluded.
// Symmetric mask => evaluate only i<j pairs (252 of them); num and denom both
// halve, ratio unchanged. dist<0.5 <=> sq<0.25; exp(-(dist/0.5)^2)=exp(-4*sq)
// => no sqrt. Two dispatches: partials (overwrite, no init) + tree reduce.

#define NPTS 24
#define BLK 128         // 2 waves per block; each wave does half the pairs
#define BATCHES_PER_BLK 64
#define LDS_STRIDE 73   // 73 mod 32 = 9 (odd) -> 2 lanes/bank on reads (free)

__global__ __launch_bounds__(BLK)
void collision_main(const float* __restrict__ pos, float2* __restrict__ ws) {
    __shared__ float lds[BATCHES_PER_BLK * LDS_STRIDE];
    const int t = threadIdx.x;                        // 0..127
    const int blockBase = blockIdx.x * BATCHES_PER_BLK;

    // --- Stage 64 batches * 72 floats = 1152 float4, coalesced (9/thread) ---
    const float4* gp = (const float4*)pos + (size_t)blockBase * 18; // 18 f4/batch
    #pragma unroll
    for (int k = 0; k < 9; ++k) {
        int f4 = t + k * BLK;         // 0..1151 ; 18 f4 per batch, no straddle
        float4 v = gp[f4];
        int b  = f4 / 18;
        int e4 = f4 % 18;
        float* dst = &lds[b * LDS_STRIDE + e4 * 4];
        dst[0] = v.x; dst[1] = v.y; dst[2] = v.z; dst[3] = v.w;
    }
    __syncthreads();

    // --- Each thread owns batch (t & 63); both waves read the same rows ---
    float px[NPTS], py[NPTS], pz[NPTS];
    const float* src = &lds[(t & 63) * LDS_STRIDE];
    #pragma unroll
    for (int i = 0; i < NPTS; ++i) {
        px[i] = src[3 * i + 0];
        py[i] = src[3 * i + 1];
        pz[i] = src[3 * i + 2];
    }

    // --- 252 pairs split 126/126 across the two waves ---
    float s = 0.0f;
    int   cc = 0;   // wave-uniform collision count via ballot (scalar pipe)
    auto acc = [&](int i, int j) {
        float dx = px[i] - px[j];
        float dy = py[i] - py[j];
        float dz = pz[i] - pz[j];
        float sq = fmaf(dx, dx, fmaf(dy, dy, dz * dz));
        bool  w  = sq < 0.25f;
        cc += (int)__popcll(__ballot(w));        // s_bcnt1_b64 + s_add
        float e  = __expf(-4.0f * sq);
        s += w ? e : 0.0f;                        // v_cndmask + v_add
    };
    if (t < 64) {
        // pairs 0..125: i=1..6 full (116 pairs) + i=7, j=8..17 (10 pairs)
        #pragma unroll
        for (int i = 1; i <= 6; ++i)
            #pragma unroll
            for (int j = i + 1; j < NPTS; ++j) {
                if (i == 2 && j == 3) continue;   // compile-time eliminated
                acc(i, j);
            }
        #pragma unroll
        for (int j = 8; j < 18; ++j) acc(7, j);
    } else {
        // pairs 126..251: i=7, j=18..23 (6 pairs) + i=8..23 (120 pairs)
        #pragma unroll
        for (int j = 18; j < NPTS; ++j) acc(7, j);
        #pragma unroll
        for (int i = 8; i < NPTS; ++i)
            #pragma unroll
            for (int j = i + 1; j < NPTS; ++j) acc(i, j);
    }

    // --- Wave reduce s; cc is already wave-uniform ---
    #pragma unroll
    for (int off = 32; off >= 1; off >>= 1)
        s += __shfl_down(s, off, 64);

    __shared__ float sred[2];
    __shared__ int   cred[2];
    const int wv = t >> 6;
    if ((t & 63) == 0) { sred[wv] = s; cred[wv] = cc; }
    __syncthreads();
    if (t == 0) {
        float2 p;
        p.x = sred[0] + sred[1];
        p.y = (float)(cred[0] + cred[1]);   // <= 16128, exact in fp32
        ws[blockIdx.x] = p;                 // overwrite: no init needed
    }
}

__global__ __launch_bounds__(256)
void collision_reduce(const float* __restrict__ ws, float* __restrict__ out) {
    // 1024 float2 partials = 512 float4; 2 float4 per thread
    const float4* p4 = (const float4*)ws;
    const int t = threadIdx.x;
    float s = 0.0f, c = 0.0f;
    #pragma unroll
    for (int k = 0; k < 2; ++k) {
        float4 v = p4[t + k * 256];
        s += v.x + v.z;
        c += v.y + v.w;
    }
    #pragma unroll
    for (int off = 32; off >= 1; off >>= 1) {
        s += __shfl_down(s, off, 64);
        c += __shfl_down(c, off, 64);
    }
    __shared__ float sb[4], cb[4];
    if ((t & 63) == 0) { sb[t >> 6] = s; cb[t >> 6] = c; }
    __syncthreads();
    if (t == 0) {
        s = sb[0] + sb[1] + sb[2] + sb[3];
        c = cb[0] + cb[1] + cb[2] + cb[3];
        float total = (c > 0.0f) ? (s / fmaxf(c, 1.0f)) : 0.0f;
        out[0] = total + 1e-6f;
    }
}

extern "C" void kernel_launch(void* const* d_in, const int* in_sizes, int n_in,
                              void* d_out, int out_size, void* d_ws, size_t ws_size,
                              hipStream_t stream) {
    const float* pos = (const float*)d_in[0];
    float* out = (float*)d_out;
    float2* ws = (float2*)d_ws;

    const int B = in_sizes[0] / (NPTS * 3);   // 65536
    const int nblocks = B / BATCHES_PER_BLK;  // 1024

    collision_main<<<nblocks, BLK, 0, stream>>>(pos, ws);
    collision_reduce<<<1, 256, 0, stream>>>((const float*)ws, out);
}